// Round 3
// baseline (797.994 us; speedup 1.0000x reference)
//
#include <hip/hip_runtime.h>

#define N_NODES 100000
#define N_EDGES 3200000
#define IN_DIM  512
#define HIDDEN  16
#define NCLS    7

#define BSH     9
#define BNODES  512                                  // nodes per bucket
#define NB      ((N_NODES + BNODES - 1) / BNODES)    // 196 buckets

#define EPB1    8192                                 // edges/block, k_bcount
#define NBLK1   ((N_EDGES + EPB1 - 1) / EPB1)        // 391
#define EPB2    4096                                 // edges/block, k_bscatter
#define NBLK2   ((N_EDGES + EPB2 - 1) / EPB2)        // 782

#define KSPLIT  4
#define KSLICE  (IN_DIM / KSPLIT)                    // 128

// ---------------- init ----------------
__global__ void k_zero(int* __restrict__ bcnt, int* __restrict__ rowstart) {
    int i = threadIdx.x;
    bcnt[i] = 0;                       // 256 entries (>= NB)
    if (i == 0) rowstart[N_NODES] = N_EDGES;
}

// ---------------- coarse bucket histogram (per-block LDS, few global atomics) ----------------
__global__ __launch_bounds__(256) void k_bcount(const int* __restrict__ dst,
                                                int* __restrict__ bcnt) {
    __shared__ int hist[256];
    int tid = threadIdx.x;
    hist[tid] = 0;
    __syncthreads();
    int e0 = blockIdx.x * EPB1;
    int n  = min(EPB1, N_EDGES - e0);
    for (int k = tid; k < n; k += 256)
        atomicAdd(&hist[dst[e0 + k] >> BSH], 1);
    __syncthreads();
    int c = hist[tid];
    if (c) atomicAdd(&bcnt[tid], c);
}

// ---------------- scan 196 bucket counts -> bstart, init global cursors ----------------
__global__ __launch_bounds__(256) void k_bscan(const int* __restrict__ bcnt,
                                               int* __restrict__ bstart,
                                               int* __restrict__ bcur) {
    __shared__ int s[256];
    int tid = threadIdx.x;
    int c = bcnt[tid];
    s[tid] = c;
    __syncthreads();
    for (int off = 1; off < 256; off <<= 1) {
        int t = (tid >= off) ? s[tid - off] : 0;
        __syncthreads();
        s[tid] += t;
        __syncthreads();
    }
    if (tid == 0) bstart[0] = 0;
    bstart[tid + 1] = s[tid];          // inclusive -> bstart[b+1]
    bcur[tid]       = s[tid] - c;      // exclusive base, running cursor
}

// ---------------- bucket scatter: block reserves contiguous runs (coalesced writes) ----------
__global__ __launch_bounds__(256) void k_bscatter(const int* __restrict__ src,
                                                  const int* __restrict__ dst,
                                                  int* __restrict__ bcur,
                                                  unsigned int* __restrict__ ebuf) {
    __shared__ unsigned int pk[EPB2];
    __shared__ unsigned char bb[EPB2];
    __shared__ int hist[256], base[256], lcur[256];
    int tid = threadIdx.x;
    hist[tid] = 0; lcur[tid] = 0;
    __syncthreads();
    int e0 = blockIdx.x * EPB2;
    int n  = min(EPB2, N_EDGES - e0);
    for (int k = tid; k < n; k += 256) {
        int d = dst[e0 + k];
        int b = d >> BSH;
        pk[k] = ((unsigned int)src[e0 + k] << BSH) | (unsigned int)(d & (BNODES - 1));
        bb[k] = (unsigned char)b;
        atomicAdd(&hist[b], 1);
    }
    __syncthreads();
    int h = hist[tid];
    base[tid] = h ? atomicAdd(&bcur[tid], h) : 0;   // one global atomic per touched bucket
    __syncthreads();
    for (int k = tid; k < n; k += 256) {
        int b = bb[k];
        int pos = atomicAdd(&lcur[b], 1);
        ebuf[base[b] + pos] = pk[k];                // block-private run -> L2 write-combine
    }
}

// ---------------- per-bucket LDS counting sort: csr_src + rowstart + dinv ----------------
__global__ __launch_bounds__(512) void k_bsort(const int* __restrict__ bstart,
                                               const unsigned int* __restrict__ ebuf,
                                               int* __restrict__ rowstart,
                                               float* __restrict__ dinv,
                                               int* __restrict__ csr_src) {
    __shared__ int hist[512], cur[512];
    int tid = threadIdx.x;
    int b   = blockIdx.x;
    int e0 = bstart[b], e1 = bstart[b + 1];
    hist[tid] = 0;
    __syncthreads();
    for (int i = e0 + tid; i < e1; i += 512)
        atomicAdd(&hist[ebuf[i] & (BNODES - 1)], 1);
    __syncthreads();
    int deg = hist[tid];
    for (int off = 1; off < 512; off <<= 1) {       // inclusive Hillis-Steele
        int t = (tid >= off) ? hist[tid - off] : 0;
        __syncthreads();
        hist[tid] += t;
        __syncthreads();
    }
    int excl = hist[tid] - deg;
    int node = (b << BSH) + tid;
    if (node < N_NODES) {
        rowstart[node] = e0 + excl;
        dinv[node]     = rsqrtf((float)(deg + 1)); // +1 self-loop
    }
    cur[tid] = excl;
    __syncthreads();
    for (int i = e0 + tid; i < e1; i += 512) {
        unsigned int p = ebuf[i];
        int pos = atomicAdd(&cur[p & (BNODES - 1)], 1);
        csr_src[e0 + pos] = (int)(p >> BSH);        // block-private region
    }
}

// ---------------- zero h1s (runs after k_bsort: h1s aliases ebuf) ----------------
__global__ __launch_bounds__(256) void k_zero_h1(float4* __restrict__ h1s4) {
    int i = blockIdx.x * 256 + threadIdx.x;
    if (i < N_NODES * 4) h1s4[i] = make_float4(0.f, 0.f, 0.f, 0.f);
}

// ---------------- layer-1 GEMM, 4-way K-split: h1s += dinv[n] * (x[:,ks] @ W1[ks,:]) ------
__global__ __launch_bounds__(256) void k_gemm1(
    const float* __restrict__ x, const float* __restrict__ W1,
    const float* __restrict__ dinv, float* __restrict__ h1s) {
    __shared__ float Xs[256 * 33];
    const int tid = threadIdx.x;
    const int bk  = blockIdx.x;
    const int n0  = (bk >> 2) * 256;
    const int ks  = bk & 3;
    const int n   = n0 + tid;
    const int kbase = ks * KSLICE;

    float acc[16];
#pragma unroll
    for (int j = 0; j < 16; ++j) acc[j] = 0.f;

    for (int kc = kbase; kc < kbase + KSLICE; kc += 32) {
        __syncthreads();
#pragma unroll
        for (int r = 0; r < 8; ++r) {
            int flat = r * 256 + tid;
            int row  = flat >> 3;
            int col  = (flat & 7) << 2;
            int gn   = n0 + row;
            if (gn < N_NODES) {
                const float4 v = *(const float4*)(x + (size_t)gn * IN_DIM + kc + col);
                float* d = &Xs[row * 33 + col];
                d[0] = v.x; d[1] = v.y; d[2] = v.z; d[3] = v.w;
            }
        }
        __syncthreads();
        if (n < N_NODES) {
#pragma unroll
            for (int i = 0; i < 32; ++i) {
                float xv = Xs[tid * 33 + i];
                const float* wr = W1 + (size_t)(kc + i) * 16;
#pragma unroll
                for (int j = 0; j < 16; ++j) acc[j] = fmaf(xv, wr[j], acc[j]);
            }
        }
    }

    if (n < N_NODES) {
        float di = dinv[n];
#pragma unroll
        for (int j = 0; j < 16; ++j)
            unsafeAtomicAdd(&h1s[(size_t)n * 16 + j], acc[j] * di);
    }
}

// ---------------- layer-1 gather-aggregate + bias + relu ----------------
__global__ __launch_bounds__(256) void k_agg1(
    const int* __restrict__ rowstart, const int* __restrict__ csr_src,
    const float* __restrict__ h1s, const float* __restrict__ dinv,
    const float* __restrict__ b1, float* __restrict__ z) {
    int gid = blockIdx.x * 256 + threadIdx.x;
    int g = gid >> 4, j = gid & 15;
    bool valid = g < N_NODES;
    int n = valid ? g : (N_NODES - 1);
    int start = rowstart[n], end = rowstart[n + 1];
    float acc = h1s[(size_t)n * 16 + j];   // self-loop term
#pragma unroll 4
    for (int i = start; i < end; ++i) {
        int s = csr_src[i];
        acc += h1s[(size_t)s * 16 + j];
    }
    if (valid) {
        float v = dinv[n] * acc + b1[j];
        z[(size_t)n * 16 + j] = fmaxf(v, 0.f);
    }
}

// ---------------- layer-2 GEMM: h2s = (z @ W2) * dinv, padded stride 8 ----------------
__global__ __launch_bounds__(256) void k_layer2(
    const float* __restrict__ z, const float* __restrict__ W2,
    const float* __restrict__ dinv, float* __restrict__ h2s) {
    int n = blockIdx.x * 256 + threadIdx.x;
    if (n >= N_NODES) return;
    float zv[16];
#pragma unroll
    for (int k = 0; k < 16; k += 4) {
        float4 v = *(const float4*)(z + (size_t)n * 16 + k);
        zv[k] = v.x; zv[k+1] = v.y; zv[k+2] = v.z; zv[k+3] = v.w;
    }
    float di = dinv[n];
    float o[8];
#pragma unroll
    for (int jj = 0; jj < 7; ++jj) {
        float a = 0.f;
#pragma unroll
        for (int k = 0; k < 16; ++k) a = fmaf(zv[k], W2[k * 7 + jj], a);
        o[jj] = a * di;
    }
    o[7] = 0.f;
    *(float4*)(h2s + (size_t)n * 8 + 0) = make_float4(o[0], o[1], o[2], o[3]);
    *(float4*)(h2s + (size_t)n * 8 + 4) = make_float4(o[4], o[5], o[6], o[7]);
}

// ---------------- layer-2 gather-aggregate + bias + log_softmax ----------------
__global__ __launch_bounds__(256) void k_agg2(
    const int* __restrict__ rowstart, const int* __restrict__ csr_src,
    const float* __restrict__ h2s, const float* __restrict__ dinv,
    const float* __restrict__ b2, float* __restrict__ out) {
    int gid = blockIdx.x * 256 + threadIdx.x;
    int g = gid >> 3, j = gid & 7;
    bool valid = g < N_NODES;
    int n = valid ? g : (N_NODES - 1);
    int start = rowstart[n], end = rowstart[n + 1];
    float acc = h2s[(size_t)n * 8 + j];    // self-loop term (slot 7 reads 0)
#pragma unroll 4
    for (int i = start; i < end; ++i) {
        int s = csr_src[i];
        acc += h2s[(size_t)s * 8 + j];
    }
    float v = dinv[n] * acc + ((j < 7) ? b2[j] : -1e30f);
    float m = v;
    m = fmaxf(m, __shfl_xor(m, 1));
    m = fmaxf(m, __shfl_xor(m, 2));
    m = fmaxf(m, __shfl_xor(m, 4));
    float e = (j < 7) ? expf(v - m) : 0.f;
    float ssum = e;
    ssum += __shfl_xor(ssum, 1);
    ssum += __shfl_xor(ssum, 2);
    ssum += __shfl_xor(ssum, 4);
    float ls = logf(ssum) + m;
    if (valid && j < 7) out[(size_t)n * 7 + j] = v - ls;
}

extern "C" void kernel_launch(void* const* d_in, const int* in_sizes, int n_in,
                              void* d_out, int out_size, void* d_ws, size_t ws_size,
                              hipStream_t stream) {
    const float* x  = (const float*)d_in[0];
    const int*   ei = (const int*)d_in[1];
    const float* W1 = (const float*)d_in[2];
    const float* b1 = (const float*)d_in[3];
    const float* W2 = (const float*)d_in[4];
    const float* b2 = (const float*)d_in[5];
    float* out = (float*)d_out;

    const int* src = ei;             // edge_index[0]
    const int* dst = ei + N_EDGES;   // edge_index[1]

    char* ws = (char*)d_ws;
    size_t o = 0;
    auto alloc = [&](size_t bytes) -> void* {
        void* p = ws + o;
        o = (o + bytes + 255) & ~(size_t)255;
        return p;
    };
    int*   bcnt     = (int*)alloc(256 * 4);
    int*   bstart   = (int*)alloc(257 * 4);
    int*   bcur     = (int*)alloc(256 * 4);
    int*   rowstart = (int*)alloc(((size_t)N_NODES + 1) * 4);
    float* dinv     = (float*)alloc((size_t)N_NODES * 4);
    int*   csr_src  = (int*)alloc((size_t)N_EDGES * 4);
    // union: ebuf (dead after k_bsort) overlaps h1s+z (live after k_bsort)
    char*  uni      = (char*)alloc((size_t)N_EDGES * 4);   // 12.8MB = 16N*4 + 16N*4
    unsigned int* ebuf = (unsigned int*)uni;
    float* h1s      = (float*)uni;
    float* z        = h1s + (size_t)N_NODES * 16;
    float* h2s      = (float*)alloc((size_t)N_NODES * 8 * 4);

    const int nb_n = (N_NODES + 255) / 256;

    k_zero    <<<1, 256, 0, stream>>>(bcnt, rowstart);
    k_bcount  <<<NBLK1, 256, 0, stream>>>(dst, bcnt);
    k_bscan   <<<1, 256, 0, stream>>>(bcnt, bstart, bcur);
    k_bscatter<<<NBLK2, 256, 0, stream>>>(src, dst, bcur, ebuf);
    k_bsort   <<<NB, 512, 0, stream>>>(bstart, ebuf, rowstart, dinv, csr_src);
    k_zero_h1 <<<(N_NODES * 4 + 255) / 256, 256, 0, stream>>>((float4*)h1s);
    k_gemm1   <<<nb_n * KSPLIT, 256, 0, stream>>>(x, W1, dinv, h1s);
    k_agg1    <<<(N_NODES * 16 + 255) / 256, 256, 0, stream>>>(rowstart, csr_src, h1s, dinv, b1, z);
    k_layer2  <<<nb_n, 256, 0, stream>>>(z, W2, dinv, h2s);
    k_agg2    <<<(N_NODES * 8 + 255) / 256, 256, 0, stream>>>(rowstart, csr_src, h2s, dinv, b2, out);
}

// Round 5
// 558.001 us; speedup vs baseline: 1.4301x; 1.4301x over previous
//
#include <hip/hip_runtime.h>

#define N_NODES 100000
#define N_EDGES 3200000
#define IN_DIM  512
#define HIDDEN  16
#define NCLS    7

#define BSH     9
#define BNODES  512                                  // nodes per bucket
#define NB      ((N_NODES + BNODES - 1) / BNODES)    // 196 buckets

#define EPB1    8192                                 // edges/block, k_bcount
#define NBLK1   ((N_EDGES + EPB1 - 1) / EPB1)        // 391
#define EPB2    4096                                 // edges/block, k_bscatter
#define NBLK2   ((N_EDGES + EPB2 - 1) / EPB2)        // 782

#define GNB     64                                   // nodes per block in k_gemm1

// ---------------- init ----------------
__global__ void k_zero(int* __restrict__ bcnt, int* __restrict__ rowstart) {
    int i = threadIdx.x;
    bcnt[i] = 0;                       // 256 entries (>= NB)
    if (i == 0) rowstart[N_NODES] = N_EDGES;
}

// ---------------- coarse bucket histogram (per-block LDS, few global atomics) ----------------
__global__ __launch_bounds__(256) void k_bcount(const int* __restrict__ dst,
                                                int* __restrict__ bcnt) {
    __shared__ int hist[256];
    int tid = threadIdx.x;
    hist[tid] = 0;
    __syncthreads();
    int e0 = blockIdx.x * EPB1;
    int n  = min(EPB1, N_EDGES - e0);
    for (int k = tid; k < n; k += 256)
        atomicAdd(&hist[dst[e0 + k] >> BSH], 1);
    __syncthreads();
    int c = hist[tid];
    if (c) atomicAdd(&bcnt[tid], c);
}

// ---------------- scan 196 bucket counts -> bstart, init global cursors ----------------
__global__ __launch_bounds__(256) void k_bscan(const int* __restrict__ bcnt,
                                               int* __restrict__ bstart,
                                               int* __restrict__ bcur) {
    __shared__ int s[256];
    int tid = threadIdx.x;
    int c = bcnt[tid];
    s[tid] = c;
    __syncthreads();
    for (int off = 1; off < 256; off <<= 1) {
        int t = (tid >= off) ? s[tid - off] : 0;
        __syncthreads();
        s[tid] += t;
        __syncthreads();
    }
    if (tid == 0) bstart[0] = 0;
    bstart[tid + 1] = s[tid];          // inclusive -> bstart[b+1]
    bcur[tid]       = s[tid] - c;      // exclusive base, running cursor
}

// ---------------- bucket scatter: block reserves contiguous runs (coalesced writes) ----------
__global__ __launch_bounds__(256) void k_bscatter(const int* __restrict__ src,
                                                  const int* __restrict__ dst,
                                                  int* __restrict__ bcur,
                                                  unsigned int* __restrict__ ebuf) {
    __shared__ unsigned int pk[EPB2];
    __shared__ unsigned char bb[EPB2];
    __shared__ int hist[256], base[256], lcur[256];
    int tid = threadIdx.x;
    hist[tid] = 0; lcur[tid] = 0;
    __syncthreads();
    int e0 = blockIdx.x * EPB2;
    int n  = min(EPB2, N_EDGES - e0);
    for (int k = tid; k < n; k += 256) {
        int d = dst[e0 + k];
        int b = d >> BSH;
        pk[k] = ((unsigned int)src[e0 + k] << BSH) | (unsigned int)(d & (BNODES - 1));
        bb[k] = (unsigned char)b;
        atomicAdd(&hist[b], 1);
    }
    __syncthreads();
    int h = hist[tid];
    base[tid] = h ? atomicAdd(&bcur[tid], h) : 0;   // one global atomic per touched bucket
    __syncthreads();
    for (int k = tid; k < n; k += 256) {
        int b = bb[k];
        int pos = atomicAdd(&lcur[b], 1);
        ebuf[base[b] + pos] = pk[k];                // block-private run -> L2 write-combine
    }
}

// ---------------- per-bucket LDS counting sort: csr_src + rowstart + dinv ----------------
__global__ __launch_bounds__(512) void k_bsort(const int* __restrict__ bstart,
                                               const unsigned int* __restrict__ ebuf,
                                               int* __restrict__ rowstart,
                                               float* __restrict__ dinv,
                                               int* __restrict__ csr_src) {
    __shared__ int hist[512], cur[512];
    int tid = threadIdx.x;
    int b   = blockIdx.x;
    int e0 = bstart[b], e1 = bstart[b + 1];
    hist[tid] = 0;
    __syncthreads();
    for (int i = e0 + tid; i < e1; i += 512)
        atomicAdd(&hist[ebuf[i] & (BNODES - 1)], 1);
    __syncthreads();
    int deg = hist[tid];
    for (int off = 1; off < 512; off <<= 1) {       // inclusive Hillis-Steele
        int t = (tid >= off) ? hist[tid - off] : 0;
        __syncthreads();
        hist[tid] += t;
        __syncthreads();
    }
    int excl = hist[tid] - deg;
    int node = (b << BSH) + tid;
    if (node < N_NODES) {
        rowstart[node] = e0 + excl;
        dinv[node]     = rsqrtf((float)(deg + 1)); // +1 self-loop
    }
    cur[tid] = excl;
    __syncthreads();
    for (int i = e0 + tid; i < e1; i += 512) {
        unsigned int p = ebuf[i];
        int pos = atomicAdd(&cur[p & (BNODES - 1)], 1);
        csr_src[e0 + pos] = (int)(p >> BSH);        // block-private region
    }
}

// ---------------- layer-1 GEMM: h1s = (x @ W1) * dinv ----------------
// 64 nodes/block, 4 threads per node each owning a j-quad over full K.
// Grid 1563 blocks, LDS 8.4KB -> ~6-8 blocks/CU resident (vs 1.5 before).
__global__ __launch_bounds__(256) void k_gemm1(
    const float* __restrict__ x, const float* __restrict__ W1,
    const float* __restrict__ dinv, float* __restrict__ h1s) {
    __shared__ float Xs[GNB * 33];
    const int tid = threadIdx.x;
    const int n0  = blockIdx.x * GNB;
    const int r   = tid & 63;          // node within block (== lane)
    const int jq  = tid >> 6;          // j-quad 0..3 (wave-uniform)
    const int n   = n0 + r;

    float acc[4] = {0.f, 0.f, 0.f, 0.f};

    for (int kc = 0; kc < IN_DIM; kc += 32) {
        __syncthreads();
        // stage 64 rows x 32 floats = 512 float4, 2 per thread, coalesced
#pragma unroll
        for (int q = 0; q < 2; ++q) {
            int flat = q * 256 + tid;   // 0..511
            int row  = flat >> 3;
            int col  = (flat & 7) << 2;
            int gn   = n0 + row;
            if (gn < N_NODES) {
                const float4 v = *(const float4*)(x + (size_t)gn * IN_DIM + kc + col);
                float* d = &Xs[row * 33 + col];
                d[0] = v.x; d[1] = v.y; d[2] = v.z; d[3] = v.w;
            }
        }
        __syncthreads();
        if (n < N_NODES) {
#pragma unroll
            for (int i = 0; i < 32; ++i) {
                float xv = Xs[r * 33 + i];
                const float* wr = W1 + (size_t)(kc + i) * 16 + jq * 4;  // wave-uniform -> s_load
                acc[0] = fmaf(xv, wr[0], acc[0]);
                acc[1] = fmaf(xv, wr[1], acc[1]);
                acc[2] = fmaf(xv, wr[2], acc[2]);
                acc[3] = fmaf(xv, wr[3], acc[3]);
            }
        }
    }

    if (n < N_NODES) {
        float di = dinv[n];
        *(float4*)(h1s + (size_t)n * 16 + jq * 4) =
            make_float4(acc[0] * di, acc[1] * di, acc[2] * di, acc[3] * di);
    }
}

// ---------------- layer-1 gather-aggregate + bias + relu ----------------
__global__ __launch_bounds__(256) void k_agg1(
    const int* __restrict__ rowstart, const int* __restrict__ csr_src,
    const float* __restrict__ h1s, const float* __restrict__ dinv,
    const float* __restrict__ b1, float* __restrict__ z) {
    int gid = blockIdx.x * 256 + threadIdx.x;
    int g = gid >> 4, j = gid & 15;
    bool valid = g < N_NODES;
    int n = valid ? g : (N_NODES - 1);
    int start = rowstart[n], end = rowstart[n + 1];
    float acc = h1s[(size_t)n * 16 + j];   // self-loop term
#pragma unroll 4
    for (int i = start; i < end; ++i) {
        int s = csr_src[i];
        acc += h1s[(size_t)s * 16 + j];
    }
    if (valid) {
        float v = dinv[n] * acc + b1[j];
        z[(size_t)n * 16 + j] = fmaxf(v, 0.f);
    }
}

// ---------------- layer-2 GEMM: h2s = (z @ W2) * dinv, padded stride 8 ----------------
__global__ __launch_bounds__(256) void k_layer2(
    const float* __restrict__ z, const float* __restrict__ W2,
    const float* __restrict__ dinv, float* __restrict__ h2s) {
    int n = blockIdx.x * 256 + threadIdx.x;
    if (n >= N_NODES) return;
    float zv[16];
#pragma unroll
    for (int k = 0; k < 16; k += 4) {
        float4 v = *(const float4*)(z + (size_t)n * 16 + k);
        zv[k] = v.x; zv[k+1] = v.y; zv[k+2] = v.z; zv[k+3] = v.w;
    }
    float di = dinv[n];
    float o[8];
#pragma unroll
    for (int jj = 0; jj < 7; ++jj) {
        float a = 0.f;
#pragma unroll
        for (int k = 0; k < 16; ++k) a = fmaf(zv[k], W2[k * 7 + jj], a);
        o[jj] = a * di;
    }
    o[7] = 0.f;
    *(float4*)(h2s + (size_t)n * 8 + 0) = make_float4(o[0], o[1], o[2], o[3]);
    *(float4*)(h2s + (size_t)n * 8 + 4) = make_float4(o[4], o[5], o[6], o[7]);
}

// ---------------- layer-2 gather-aggregate + bias + log_softmax ----------------
__global__ __launch_bounds__(256) void k_agg2(
    const int* __restrict__ rowstart, const int* __restrict__ csr_src,
    const float* __restrict__ h2s, const float* __restrict__ dinv,
    const float* __restrict__ b2, float* __restrict__ out) {
    int gid = blockIdx.x * 256 + threadIdx.x;
    int g = gid >> 3, j = gid & 7;
    bool valid = g < N_NODES;
    int n = valid ? g : (N_NODES - 1);
    int start = rowstart[n], end = rowstart[n + 1];
    float acc = h2s[(size_t)n * 8 + j];    // self-loop term (slot 7 reads 0)
#pragma unroll 4
    for (int i = start; i < end; ++i) {
        int s = csr_src[i];
        acc += h2s[(size_t)s * 8 + j];
    }
    float v = dinv[n] * acc + ((j < 7) ? b2[j] : -1e30f);
    float m = v;
    m = fmaxf(m, __shfl_xor(m, 1));
    m = fmaxf(m, __shfl_xor(m, 2));
    m = fmaxf(m, __shfl_xor(m, 4));
    float e = (j < 7) ? expf(v - m) : 0.f;
    float ssum = e;
    ssum += __shfl_xor(ssum, 1);
    ssum += __shfl_xor(ssum, 2);
    ssum += __shfl_xor(ssum, 4);
    float ls = logf(ssum) + m;
    if (valid && j < 7) out[(size_t)n * 7 + j] = v - ls;
}

extern "C" void kernel_launch(void* const* d_in, const int* in_sizes, int n_in,
                              void* d_out, int out_size, void* d_ws, size_t ws_size,
                              hipStream_t stream) {
    const float* x  = (const float*)d_in[0];
    const int*   ei = (const int*)d_in[1];
    const float* W1 = (const float*)d_in[2];
    const float* b1 = (const float*)d_in[3];
    const float* W2 = (const float*)d_in[4];
    const float* b2 = (const float*)d_in[5];
    float* out = (float*)d_out;

    const int* src = ei;             // edge_index[0]
    const int* dst = ei + N_EDGES;   // edge_index[1]

    char* ws = (char*)d_ws;
    size_t o = 0;
    auto alloc = [&](size_t bytes) -> void* {
        void* p = ws + o;
        o = (o + bytes + 255) & ~(size_t)255;
        return p;
    };
    int*   bcnt     = (int*)alloc(256 * 4);
    int*   bstart   = (int*)alloc(257 * 4);
    int*   bcur     = (int*)alloc(256 * 4);
    int*   rowstart = (int*)alloc(((size_t)N_NODES + 1) * 4);
    float* dinv     = (float*)alloc((size_t)N_NODES * 4);
    int*   csr_src  = (int*)alloc((size_t)N_EDGES * 4);
    // union: ebuf (dead after k_bsort) overlaps h1s+z (live after k_bsort)
    char*  uni      = (char*)alloc((size_t)N_EDGES * 4);   // 12.8MB = 16N*4 + 16N*4
    unsigned int* ebuf = (unsigned int*)uni;
    float* h1s      = (float*)uni;
    float* z        = h1s + (size_t)N_NODES * 16;
    float* h2s      = (float*)alloc((size_t)N_NODES * 8 * 4);

    const int nb_n = (N_NODES + 255) / 256;

    k_zero    <<<1, 256, 0, stream>>>(bcnt, rowstart);
    k_bcount  <<<NBLK1, 256, 0, stream>>>(dst, bcnt);
    k_bscan   <<<1, 256, 0, stream>>>(bcnt, bstart, bcur);
    k_bscatter<<<NBLK2, 256, 0, stream>>>(src, dst, bcur, ebuf);
    k_bsort   <<<NB, 512, 0, stream>>>(bstart, ebuf, rowstart, dinv, csr_src);
    k_gemm1   <<<(N_NODES + GNB - 1) / GNB, 256, 0, stream>>>(x, W1, dinv, h1s);
    k_agg1    <<<(N_NODES * 16 + 255) / 256, 256, 0, stream>>>(rowstart, csr_src, h1s, dinv, b1, z);
    k_layer2  <<<nb_n, 256, 0, stream>>>(z, W2, dinv, h2s);
    k_agg2    <<<(N_NODES * 8 + 255) / 256, 256, 0, stream>>>(rowstart, csr_src, h2s, dinv, b2, out);
}

// Round 6
// 462.734 us; speedup vs baseline: 1.7245x; 1.2059x over previous
//
#include <hip/hip_runtime.h>

#define N_NODES 100000
#define N_EDGES 3200000
#define IN_DIM  512
#define HIDDEN  16
#define NCLS    7

#define BSH     9
#define BNODES  512                                  // nodes per bucket
#define NB      ((N_NODES + BNODES - 1) / BNODES)    // 196 buckets

#define EPB1    8192                                 // edges/block, k_bcount
#define NBLK1   ((N_EDGES + EPB1 - 1) / EPB1)        // 391
#define EPB2    4096                                 // edges/block, k_bscatter
#define NBLK2   ((N_EDGES + EPB2 - 1) / EPB2)        // 782

#define GEMM1_BLOCKS 512                             // 2048 waves = 8 waves/CU resident

// ---------------- init ----------------
__global__ void k_zero(int* __restrict__ bcnt, int* __restrict__ rowstart) {
    int i = threadIdx.x;
    bcnt[i] = 0;                       // 256 entries (>= NB)
    if (i == 0) rowstart[N_NODES] = N_EDGES;
}

// ---------------- coarse bucket histogram (per-block LDS, few global atomics) ----------------
__global__ __launch_bounds__(256) void k_bcount(const int* __restrict__ dst,
                                                int* __restrict__ bcnt) {
    __shared__ int hist[256];
    int tid = threadIdx.x;
    hist[tid] = 0;
    __syncthreads();
    int e0 = blockIdx.x * EPB1;
    int n  = min(EPB1, N_EDGES - e0);
    for (int k = tid; k < n; k += 256)
        atomicAdd(&hist[dst[e0 + k] >> BSH], 1);
    __syncthreads();
    int c = hist[tid];
    if (c) atomicAdd(&bcnt[tid], c);
}

// ---------------- scan 196 bucket counts -> bstart, init global cursors ----------------
__global__ __launch_bounds__(256) void k_bscan(const int* __restrict__ bcnt,
                                               int* __restrict__ bstart,
                                               int* __restrict__ bcur) {
    __shared__ int s[256];
    int tid = threadIdx.x;
    int c = bcnt[tid];
    s[tid] = c;
    __syncthreads();
    for (int off = 1; off < 256; off <<= 1) {
        int t = (tid >= off) ? s[tid - off] : 0;
        __syncthreads();
        s[tid] += t;
        __syncthreads();
    }
    if (tid == 0) bstart[0] = 0;
    bstart[tid + 1] = s[tid];          // inclusive -> bstart[b+1]
    bcur[tid]       = s[tid] - c;      // exclusive base, running cursor
}

// ---------------- bucket scatter: block reserves contiguous runs (coalesced writes) ----------
__global__ __launch_bounds__(256) void k_bscatter(const int* __restrict__ src,
                                                  const int* __restrict__ dst,
                                                  int* __restrict__ bcur,
                                                  unsigned int* __restrict__ ebuf) {
    __shared__ unsigned int pk[EPB2];
    __shared__ unsigned char bb[EPB2];
    __shared__ int hist[256], base[256], lcur[256];
    int tid = threadIdx.x;
    hist[tid] = 0; lcur[tid] = 0;
    __syncthreads();
    int e0 = blockIdx.x * EPB2;
    int n  = min(EPB2, N_EDGES - e0);
    for (int k = tid; k < n; k += 256) {
        int d = dst[e0 + k];
        int b = d >> BSH;
        pk[k] = ((unsigned int)src[e0 + k] << BSH) | (unsigned int)(d & (BNODES - 1));
        bb[k] = (unsigned char)b;
        atomicAdd(&hist[b], 1);
    }
    __syncthreads();
    int h = hist[tid];
    base[tid] = h ? atomicAdd(&bcur[tid], h) : 0;   // one global atomic per touched bucket
    __syncthreads();
    for (int k = tid; k < n; k += 256) {
        int b = bb[k];
        int pos = atomicAdd(&lcur[b], 1);
        ebuf[base[b] + pos] = pk[k];                // block-private run -> L2 write-combine
    }
}

// ---------------- per-bucket LDS counting sort: csr_src + rowstart + dinv ----------------
__global__ __launch_bounds__(512) void k_bsort(const int* __restrict__ bstart,
                                               const unsigned int* __restrict__ ebuf,
                                               int* __restrict__ rowstart,
                                               float* __restrict__ dinv,
                                               int* __restrict__ csr_src) {
    __shared__ int hist[512], cur[512];
    int tid = threadIdx.x;
    int b   = blockIdx.x;
    int e0 = bstart[b], e1 = bstart[b + 1];
    hist[tid] = 0;
    __syncthreads();
    for (int i = e0 + tid; i < e1; i += 512)
        atomicAdd(&hist[ebuf[i] & (BNODES - 1)], 1);
    __syncthreads();
    int deg = hist[tid];
    for (int off = 1; off < 512; off <<= 1) {       // inclusive Hillis-Steele
        int t = (tid >= off) ? hist[tid - off] : 0;
        __syncthreads();
        hist[tid] += t;
        __syncthreads();
    }
    int excl = hist[tid] - deg;
    int node = (b << BSH) + tid;
    if (node < N_NODES) {
        rowstart[node] = e0 + excl;
        dinv[node]     = rsqrtf((float)(deg + 1)); // +1 self-loop
    }
    cur[tid] = excl;
    __syncthreads();
    for (int i = e0 + tid; i < e1; i += 512) {
        unsigned int p = ebuf[i];
        int pos = atomicAdd(&cur[p & (BNODES - 1)], 1);
        csr_src[e0 + pos] = (int)(p >> BSH);        // block-private region
    }
}

// ---------------- layer-1 GEMM: h1s = (x @ W1) * dinv ----------------
// One wave per node. Lane l owns k in {4l..4l+3} u {256+4l..256+4l+3}; W1 fragment
// (128 floats) lives in registers. No LDS, no barriers. Value-halving butterfly
// (17 shuffles) leaves lane l with output j = l&15.
__global__ __launch_bounds__(256, 2) void k_gemm1(
    const float* __restrict__ x, const float* __restrict__ W1,
    const float* __restrict__ dinv, float* __restrict__ h1s) {
    const int tid = threadIdx.x;
    const int l   = tid & 63;
    const int wid = blockIdx.x * 4 + (tid >> 6);
    const int nw  = GEMM1_BLOCKS * 4;

    // preload W1 fragment into registers (one-time, L2-hot after first wave)
    float w[8][16];
#pragma unroll
    for (int q = 0; q < 4; ++q) {
#pragma unroll
        for (int c = 0; c < 4; ++c) {
            float4 t0 = *(const float4*)(W1 + (size_t)(4 * l + q) * 16 + 4 * c);
            w[q][4*c+0] = t0.x; w[q][4*c+1] = t0.y; w[q][4*c+2] = t0.z; w[q][4*c+3] = t0.w;
            float4 t1 = *(const float4*)(W1 + (size_t)(256 + 4 * l + q) * 16 + 4 * c);
            w[4+q][4*c+0] = t1.x; w[4+q][4*c+1] = t1.y; w[4+q][4*c+2] = t1.z; w[4+q][4*c+3] = t1.w;
        }
    }

    const int b0 = l & 1, b1 = (l >> 1) & 1, b2 = (l >> 2) & 1, b3 = (l >> 3) & 1;

    int n = wid;
    if (n >= N_NODES) return;
    const float* xr = x + (size_t)n * IN_DIM;
    float4 v0 = *(const float4*)(xr + 4 * l);
    float4 v1 = *(const float4*)(xr + 256 + 4 * l);

    for (;;) {
        // prefetch next node's row (clamped; harmless re-read on last iter)
        int n2 = n + nw;
        int np = (n2 < N_NODES) ? n2 : n;
        const float* xp = x + (size_t)np * IN_DIM;
        float4 u0 = *(const float4*)(xp + 4 * l);
        float4 u1 = *(const float4*)(xp + 256 + 4 * l);

        float p[16];
#pragma unroll
        for (int j = 0; j < 16; ++j) {
            float a = v0.x * w[0][j];
            a = fmaf(v0.y, w[1][j], a);
            a = fmaf(v0.z, w[2][j], a);
            a = fmaf(v0.w, w[3][j], a);
            a = fmaf(v1.x, w[4][j], a);
            a = fmaf(v1.y, w[5][j], a);
            a = fmaf(v1.z, w[6][j], a);
            a = fmaf(v1.w, w[7][j], a);
            p[j] = a;
        }

        // value-halving butterfly: 16 vals -> 1 val/lane (j = l&15)
        float q8[8];
#pragma unroll
        for (int m = 0; m < 8; ++m) {
            float keep = b0 ? p[2*m+1] : p[2*m];
            float give = b0 ? p[2*m]   : p[2*m+1];
            q8[m] = keep + __shfl_xor(give, 1);
        }
        float r4[4];
#pragma unroll
        for (int t = 0; t < 4; ++t) {
            float keep = b1 ? q8[2*t+1] : q8[2*t];
            float give = b1 ? q8[2*t]   : q8[2*t+1];
            r4[t] = keep + __shfl_xor(give, 2);
        }
        float s2[2];
#pragma unroll
        for (int u = 0; u < 2; ++u) {
            float keep = b2 ? r4[2*u+1] : r4[2*u];
            float give = b2 ? r4[2*u]   : r4[2*u+1];
            s2[u] = keep + __shfl_xor(give, 4);
        }
        float t0 = (b3 ? s2[1] : s2[0]) + __shfl_xor(b3 ? s2[0] : s2[1], 8);
        t0 += __shfl_xor(t0, 16);
        t0 += __shfl_xor(t0, 32);

        float di = dinv[n];
        if (l < 16) h1s[(size_t)n * 16 + l] = t0 * di;

        n = n2;
        if (n >= N_NODES) break;
        v0 = u0; v1 = u1;
    }
}

// ---------------- layer-1 gather-aggregate + bias + relu ----------------
__global__ __launch_bounds__(256) void k_agg1(
    const int* __restrict__ rowstart, const int* __restrict__ csr_src,
    const float* __restrict__ h1s, const float* __restrict__ dinv,
    const float* __restrict__ b1, float* __restrict__ z) {
    int gid = blockIdx.x * 256 + threadIdx.x;
    int g = gid >> 4, j = gid & 15;
    bool valid = g < N_NODES;
    int n = valid ? g : (N_NODES - 1);
    int start = rowstart[n], end = rowstart[n + 1];
    float acc = h1s[(size_t)n * 16 + j];   // self-loop term
#pragma unroll 4
    for (int i = start; i < end; ++i) {
        int s = csr_src[i];
        acc += h1s[(size_t)s * 16 + j];
    }
    if (valid) {
        float v = dinv[n] * acc + b1[j];
        z[(size_t)n * 16 + j] = fmaxf(v, 0.f);
    }
}

// ---------------- layer-2 GEMM: h2s = (z @ W2) * dinv, padded stride 8 ----------------
__global__ __launch_bounds__(256) void k_layer2(
    const float* __restrict__ z, const float* __restrict__ W2,
    const float* __restrict__ dinv, float* __restrict__ h2s) {
    int n = blockIdx.x * 256 + threadIdx.x;
    if (n >= N_NODES) return;
    float zv[16];
#pragma unroll
    for (int k = 0; k < 16; k += 4) {
        float4 v = *(const float4*)(z + (size_t)n * 16 + k);
        zv[k] = v.x; zv[k+1] = v.y; zv[k+2] = v.z; zv[k+3] = v.w;
    }
    float di = dinv[n];
    float o[8];
#pragma unroll
    for (int jj = 0; jj < 7; ++jj) {
        float a = 0.f;
#pragma unroll
        for (int k = 0; k < 16; ++k) a = fmaf(zv[k], W2[k * 7 + jj], a);
        o[jj] = a * di;
    }
    o[7] = 0.f;
    *(float4*)(h2s + (size_t)n * 8 + 0) = make_float4(o[0], o[1], o[2], o[3]);
    *(float4*)(h2s + (size_t)n * 8 + 4) = make_float4(o[4], o[5], o[6], o[7]);
}

// ---------------- layer-2 gather-aggregate + bias + log_softmax ----------------
__global__ __launch_bounds__(256) void k_agg2(
    const int* __restrict__ rowstart, const int* __restrict__ csr_src,
    const float* __restrict__ h2s, const float* __restrict__ dinv,
    const float* __restrict__ b2, float* __restrict__ out) {
    int gid = blockIdx.x * 256 + threadIdx.x;
    int g = gid >> 3, j = gid & 7;
    bool valid = g < N_NODES;
    int n = valid ? g : (N_NODES - 1);
    int start = rowstart[n], end = rowstart[n + 1];
    float acc = h2s[(size_t)n * 8 + j];    // self-loop term (slot 7 reads 0)
#pragma unroll 4
    for (int i = start; i < end; ++i) {
        int s = csr_src[i];
        acc += h2s[(size_t)s * 8 + j];
    }
    float v = dinv[n] * acc + ((j < 7) ? b2[j] : -1e30f);
    float m = v;
    m = fmaxf(m, __shfl_xor(m, 1));
    m = fmaxf(m, __shfl_xor(m, 2));
    m = fmaxf(m, __shfl_xor(m, 4));
    float e = (j < 7) ? expf(v - m) : 0.f;
    float ssum = e;
    ssum += __shfl_xor(ssum, 1);
    ssum += __shfl_xor(ssum, 2);
    ssum += __shfl_xor(ssum, 4);
    float ls = logf(ssum) + m;
    if (valid && j < 7) out[(size_t)n * 7 + j] = v - ls;
}

extern "C" void kernel_launch(void* const* d_in, const int* in_sizes, int n_in,
                              void* d_out, int out_size, void* d_ws, size_t ws_size,
                              hipStream_t stream) {
    const float* x  = (const float*)d_in[0];
    const int*   ei = (const int*)d_in[1];
    const float* W1 = (const float*)d_in[2];
    const float* b1 = (const float*)d_in[3];
    const float* W2 = (const float*)d_in[4];
    const float* b2 = (const float*)d_in[5];
    float* out = (float*)d_out;

    const int* src = ei;             // edge_index[0]
    const int* dst = ei + N_EDGES;   // edge_index[1]

    char* ws = (char*)d_ws;
    size_t o = 0;
    auto alloc = [&](size_t bytes) -> void* {
        void* p = ws + o;
        o = (o + bytes + 255) & ~(size_t)255;
        return p;
    };
    int*   bcnt     = (int*)alloc(256 * 4);
    int*   bstart   = (int*)alloc(257 * 4);
    int*   bcur     = (int*)alloc(256 * 4);
    int*   rowstart = (int*)alloc(((size_t)N_NODES + 1) * 4);
    float* dinv     = (float*)alloc((size_t)N_NODES * 4);
    int*   csr_src  = (int*)alloc((size_t)N_EDGES * 4);
    // union: ebuf (dead after k_bsort) overlaps h1s+z (live after k_bsort)
    char*  uni      = (char*)alloc((size_t)N_EDGES * 4);   // 12.8MB = 16N*4 + 16N*4
    unsigned int* ebuf = (unsigned int*)uni;
    float* h1s      = (float*)uni;
    float* z        = h1s + (size_t)N_NODES * 16;
    float* h2s      = (float*)alloc((size_t)N_NODES * 8 * 4);

    const int nb_n = (N_NODES + 255) / 256;

    k_zero    <<<1, 256, 0, stream>>>(bcnt, rowstart);
    k_bcount  <<<NBLK1, 256, 0, stream>>>(dst, bcnt);
    k_bscan   <<<1, 256, 0, stream>>>(bcnt, bstart, bcur);
    k_bscatter<<<NBLK2, 256, 0, stream>>>(src, dst, bcur, ebuf);
    k_bsort   <<<NB, 512, 0, stream>>>(bstart, ebuf, rowstart, dinv, csr_src);
    k_gemm1   <<<GEMM1_BLOCKS, 256, 0, stream>>>(x, W1, dinv, h1s);
    k_agg1    <<<(N_NODES * 16 + 255) / 256, 256, 0, stream>>>(rowstart, csr_src, h1s, dinv, b1, z);
    k_layer2  <<<nb_n, 256, 0, stream>>>(z, W2, dinv, h2s);
    k_agg2    <<<(N_NODES * 8 + 255) / 256, 256, 0, stream>>>(rowstart, csr_src, h2s, dinv, b2, out);
}